// Round 2
// baseline (817.899 us; speedup 1.0000x reference)
//
#include <hip/hip_runtime.h>
#include <hip/hip_bf16.h>

#define SCALE_SILU (1.0f / 0.6f)

using f32x4  = __attribute__((ext_vector_type(4))) float;
using short8 = __attribute__((ext_vector_type(8))) short;

__device__ __forceinline__ short f2bf(float f) {
    union { __hip_bfloat16 b; short s; } u;
    u.b = __float2bfloat16(f);   // round-to-nearest-even
    return u.s;
}

// Edges tiled 16 per wave. K = 144 padded to 160 = 5 MFMA steps of 32.
// A (x) layout per lane: row = lane&15 (edge), k = (lane>>4)*8 + j (8 consecutive).
// B (W) layout per lane: col = lane&15 (out feat), k = (lane>>4)*8 + j.
// D layout per lane: col = lane&15, row = (lane>>4)*4 + i  [m89-verified].
__global__ __launch_bounds__(256) void edge_mlp_kernel(
    const float* __restrict__ h,      // (A, 64)
    const float* __restrict__ m,      // (E, 16)
    const int*   __restrict__ eidx,   // (2, E)
    const float* __restrict__ W,      // (144, 64)
    float*       __restrict__ out,    // (E, 64)
    int E, int A)
{
    __shared__ short Wlds[64 * 160];  // W transposed [o][k], bf16 bits, k padded to 160

    const int tid = threadIdx.x;

    // Stage W -> LDS (transposed, bf16). One-time per block; W is L2-resident.
    for (int i = tid; i < 64 * 160; i += 256) {
        int o = i / 160;
        int k = i - o * 160;
        float v = (k < 144) ? W[k * 64 + o] : 0.0f;
        Wlds[o * 160 + k] = f2bf(v);
    }
    __syncthreads();

    const int lane = tid & 63;
    const int wave = tid >> 6;
    const int l15  = lane & 15;
    const int kq   = lane >> 4;   // 0..3

    // B fragments in registers: [kk][ntile], reused for all edge tiles.
    short8 bfrag[5][4];
#pragma unroll
    for (int kk = 0; kk < 5; ++kk) {
#pragma unroll
        for (int nt = 0; nt < 4; ++nt) {
            int col = nt * 16 + l15;
            int k0  = kk * 32 + kq * 8;
            bfrag[kk][nt] = *reinterpret_cast<const short8*>(&Wlds[col * 160 + k0]);
        }
    }

    const int ntiles = (E + 15) >> 4;
    const int gwaves = gridDim.x << 2;

    for (int tile = (blockIdx.x << 2) + wave; tile < ntiles; tile += gwaves) {
        const int e0 = tile << 4;
        int e  = e0 + l15;
        int ec = (e < E) ? e : (E - 1);
        int s  = eidx[ec];          // source atom (row 0 of edge_index)
        int t  = eidx[E + ec];      // target atom (row 1)
        // Defensive clamp: an OOB gather would fault the whole container.
        s = (s < 0) ? 0 : (s >= A ? A - 1 : s);
        t = (t < 0) ? 0 : (t >= A ? A - 1 : t);

        f32x4 acc[4];
#pragma unroll
        for (int nt = 0; nt < 4; ++nt) acc[nt] = (f32x4){0.f, 0.f, 0.f, 0.f};

#pragma unroll
        for (int kk = 0; kk < 5; ++kk) {
            f32x4 v0, v1;
            if (kk < 4) {
                // kk 0,1 -> h_s (k 0..63); kk 2,3 -> h_t (k 64..127)
                const float* p = h + (size_t)(kk < 2 ? s : t) * 64 + (kk & 1) * 32 + kq * 8;
                v0 = *reinterpret_cast<const f32x4*>(p);
                v1 = *reinterpret_cast<const f32x4*>(p + 4);
            } else {
                // kk 4: k 128..143 -> m row (16 f32); k 144..159 -> zero pad
                if (kq < 2) {
                    const float* p = m + (size_t)ec * 16 + kq * 8;
                    v0 = *reinterpret_cast<const f32x4*>(p);
                    v1 = *reinterpret_cast<const f32x4*>(p + 4);
                } else {
                    v0 = (f32x4){0.f, 0.f, 0.f, 0.f};
                    v1 = (f32x4){0.f, 0.f, 0.f, 0.f};
                }
            }
            short8 afrag;
            afrag[0] = f2bf(v0[0]); afrag[1] = f2bf(v0[1]);
            afrag[2] = f2bf(v0[2]); afrag[3] = f2bf(v0[3]);
            afrag[4] = f2bf(v1[0]); afrag[5] = f2bf(v1[1]);
            afrag[6] = f2bf(v1[2]); afrag[7] = f2bf(v1[3]);
#pragma unroll
            for (int nt = 0; nt < 4; ++nt)
                acc[nt] = __builtin_amdgcn_mfma_f32_16x16x32_bf16(
                    afrag, bfrag[kk][nt], acc[nt], 0, 0, 0);
        }

        // Epilogue: ScaledSiLU + store. Row (edge) = e0 + kq*4 + i, col = nt*16 + l15.
#pragma unroll
        for (int i = 0; i < 4; ++i) {
            int er = e0 + kq * 4 + i;
            if (er < E) {
#pragma unroll
                for (int nt = 0; nt < 4; ++nt) {
                    float y = acc[nt][i];
                    float r = (y * SCALE_SILU) / (1.0f + __expf(-y));
                    out[(size_t)er * 64 + nt * 16 + l15] = r;
                }
            }
        }
    }
}

extern "C" void kernel_launch(void* const* d_in, const int* in_sizes, int n_in,
                              void* d_out, int out_size, void* d_ws, size_t ws_size,
                              hipStream_t stream) {
    const float* h    = (const float*)d_in[0];
    const float* m    = (const float*)d_in[1];
    const int*   eidx = (const int*)d_in[2];
    const float* W    = (const float*)d_in[3];
    float*       out  = (float*)d_out;

    const int E = in_sizes[1] / 16;     // num_edges
    const int A = in_sizes[0] / 64;     // num_atoms
    const int ntiles = (E + 15) / 16;
    int blocks = (ntiles + 3) / 4;
    if (blocks > 2048) blocks = 2048;

    hipLaunchKernelGGL(edge_mlp_kernel, dim3(blocks), dim3(256), 0, stream,
                       h, m, eidx, W, out, E, A);
}